// Round 1
// 215.815 us; speedup vs baseline: 1.2459x; 1.2459x over previous
//
#include <hip/hip_runtime.h>

typedef unsigned int u32;
typedef unsigned short u16;
typedef long long i64;

#define NNODES 50000
#define NEDGES 800000
#define DF 128
#define CAP 64   // bucket capacity: Poisson(16) tail P(c>64) ~ 2e-18/node

typedef __bf16 bf16x8 __attribute__((ext_vector_type(8)));
typedef float f32x4 __attribute__((ext_vector_type(4)));

__device__ __forceinline__ u16 f2bf(float f) {
    union { float f; u32 i; } v; v.f = f;
    u32 u = v.i;
    return (u16)((u + 0x7fffu + ((u >> 16) & 1u)) >> 16);  // RNE
}

// ------- 0. detect index dtype: int64 -> odd u32 words all zero ---------
__global__ __launch_bounds__(256) void detect_kernel(const u32* __restrict__ src_w,
                                                     u32* __restrict__ flag) {
    __shared__ int any_nz;
    if (threadIdx.x == 0) any_nz = 0;
    __syncthreads();
    if (src_w[2 * threadIdx.x + 1] != 0u) atomicOr(&any_nz, 1);
    __syncthreads();
    if (threadIdx.x == 0) *flag = (any_nz == 0) ? 1u : 0u;  // 1 = int64
}

// ------- 1. fused hist+fill into fixed-capacity buckets -----------------
// pos = atomicAdd(counts[d]) serves as both slot index and final count.
// Replaces the old hist -> scan -> fill CSR pipeline (3 kernels -> 1).
__global__ __launch_bounds__(256) void fill_kernel(const void* __restrict__ src,
                                                   const void* __restrict__ dst,
                                                   const u32* __restrict__ flag,
                                                   u32* __restrict__ counts,
                                                   int* __restrict__ edge_src) {
    int e0 = blockIdx.x * 1024 + threadIdx.x;
    bool is64 = (*flag != 0u);
    if (e0 + 768 < NEDGES) {
        // full block: hoist 4 independent loads, then 4 atomics in flight
        int s0, s1, s2, s3, d0, d1, d2, d3;
        if (is64) {
            s0 = (int)((const i64*)src)[e0];       d0 = (int)((const i64*)dst)[e0];
            s1 = (int)((const i64*)src)[e0 + 256]; d1 = (int)((const i64*)dst)[e0 + 256];
            s2 = (int)((const i64*)src)[e0 + 512]; d2 = (int)((const i64*)dst)[e0 + 512];
            s3 = (int)((const i64*)src)[e0 + 768]; d3 = (int)((const i64*)dst)[e0 + 768];
        } else {
            s0 = ((const int*)src)[e0];       d0 = ((const int*)dst)[e0];
            s1 = ((const int*)src)[e0 + 256]; d1 = ((const int*)dst)[e0 + 256];
            s2 = ((const int*)src)[e0 + 512]; d2 = ((const int*)dst)[e0 + 512];
            s3 = ((const int*)src)[e0 + 768]; d3 = ((const int*)dst)[e0 + 768];
        }
        u32 p0 = atomicAdd(&counts[d0], 1u);
        u32 p1 = atomicAdd(&counts[d1], 1u);
        u32 p2 = atomicAdd(&counts[d2], 1u);
        u32 p3 = atomicAdd(&counts[d3], 1u);
        if (p0 < CAP) edge_src[(d0 << 6) + (int)p0] = s0;
        if (p1 < CAP) edge_src[(d1 << 6) + (int)p1] = s1;
        if (p2 < CAP) edge_src[(d2 << 6) + (int)p2] = s2;
        if (p3 < CAP) edge_src[(d3 << 6) + (int)p3] = s3;
    } else {
        for (int k = 0; k < 4; ++k) {
            int e = e0 + k * 256;
            if (e >= NEDGES) break;
            int s, d;
            if (is64) { s = (int)((const i64*)src)[e]; d = (int)((const i64*)dst)[e]; }
            else      { s = ((const int*)src)[e];      d = ((const int*)dst)[e]; }
            u32 pos = atomicAdd(&counts[d], 1u);
            if (pos < CAP) edge_src[(d << 6) + (int)pos] = s;
        }
    }
}

// ------- 2. gather: dedup + sum + combine -> X (bf16, in ws) ------------
// One wave per dst node, entirely wave-private (no block barriers).
// Dedup via shuffle broadcast (cap 64 -> one candidate per lane), then
// ballot-compact into LDS, then 8-deep-unrolled row loads for ILP.
__global__ __launch_bounds__(256) void gather_kernel(const float* __restrict__ nf,
                                                     const u32* __restrict__ counts,
                                                     const int* __restrict__ edge_src,
                                                     const float* __restrict__ alpha,
                                                     u16* __restrict__ X) {
    __shared__ __align__(16) int s_kept[4][CAP];
    int w = threadIdx.x >> 6, lane = threadIdx.x & 63;
    int d = blockIdx.x * 4 + w;          // grid = NNODES/4 exactly
    int c = (int)counts[d];
    int cc = c < CAP ? c : CAP;

    // issue the dst row + alpha loads early; they overlap the dedup phase
    float al = 1.0f + alpha[0];
    float2 dv = *(const float2*)(nf + (size_t)d * DF + 2 * lane);

    int si = 0;
    bool k = false;
    if (lane < cc) { si = edge_src[(d << 6) + lane]; k = true; }
    // drop lane if any earlier lane holds the same src (wave-uniform bound)
    for (int j = 0; j < cc - 1; ++j) {
        int v = __shfl(si, j, 64);
        if (j < lane && v == si) k = false;
    }
    unsigned long long m = __ballot(k);
    if (k) s_kept[w][__popcll(m & ((1ull << lane) - 1ull))] = si;
    int nk = __popcll(m);
    __builtin_amdgcn_wave_barrier();     // wave-private LDS: no __syncthreads

    float a0 = 0.f, a1 = 0.f;            // this lane's two feature columns
    int i = 0;
    for (; i + 8 <= nk; i += 8) {        // 8 independent 512B row loads in flight
        int4 q0 = *(const int4*)&s_kept[w][i];
        int4 q1 = *(const int4*)&s_kept[w][i + 4];
        float2 v0 = *(const float2*)(nf + (size_t)q0.x * DF + 2 * lane);
        float2 v1 = *(const float2*)(nf + (size_t)q0.y * DF + 2 * lane);
        float2 v2 = *(const float2*)(nf + (size_t)q0.z * DF + 2 * lane);
        float2 v3 = *(const float2*)(nf + (size_t)q0.w * DF + 2 * lane);
        float2 v4 = *(const float2*)(nf + (size_t)q1.x * DF + 2 * lane);
        float2 v5 = *(const float2*)(nf + (size_t)q1.y * DF + 2 * lane);
        float2 v6 = *(const float2*)(nf + (size_t)q1.z * DF + 2 * lane);
        float2 v7 = *(const float2*)(nf + (size_t)q1.w * DF + 2 * lane);
        a0 += ((v0.x + v1.x) + (v2.x + v3.x)) + ((v4.x + v5.x) + (v6.x + v7.x));
        a1 += ((v0.y + v1.y) + (v2.y + v3.y)) + ((v4.y + v5.y) + (v6.y + v7.y));
    }
    for (; i + 4 <= nk; i += 4) {
        int4 q = *(const int4*)&s_kept[w][i];
        float2 v0 = *(const float2*)(nf + (size_t)q.x * DF + 2 * lane);
        float2 v1 = *(const float2*)(nf + (size_t)q.y * DF + 2 * lane);
        float2 v2 = *(const float2*)(nf + (size_t)q.z * DF + 2 * lane);
        float2 v3 = *(const float2*)(nf + (size_t)q.w * DF + 2 * lane);
        a0 += (v0.x + v1.x) + (v2.x + v3.x);
        a1 += (v0.y + v1.y) + (v2.y + v3.y);
    }
    for (; i < nk; ++i) {
        int s = s_kept[w][i];
        float2 v = *(const float2*)(nf + (size_t)s * DF + 2 * lane);
        a0 += v.x; a1 += v.y;
    }

    u32 pk = (u32)f2bf(fmaf(al, dv.x, a0)) | ((u32)f2bf(fmaf(al, dv.y, a1)) << 16);
    *(u32*)(X + (size_t)d * DF + 2 * lane) = pk;
}

// ------- 3. W pre-convert: W[k][n] f32 -> WT[n][k] bf16 -----------------
__global__ __launch_bounds__(256) void wconv_kernel(const float* __restrict__ W1,
                                                    const float* __restrict__ W2,
                                                    u16* __restrict__ W1T,
                                                    u16* __restrict__ W2T) {
    int i = blockIdx.x * 256 + threadIdx.x;   // 32768 threads
    const float* W = (i < 16384) ? W1 : W2;
    u16* T = (i < 16384) ? W1T : W2T;
    int j = i & 16383;
    int n = j >> 7, k = j & 127;
    T[j] = f2bf(W[k * 128 + n]);
}

// ------- 4. fused MFMA MLP: O = relu(X@W1+b1)@W2 + b2  (bf16 in, f32 out)
// 256 threads (4 waves), 64 rows/block. All staging is pure uint4 copies
// (W pre-converted to bf16-transposed). sA reused for hidden H.
// mfma_f32_16x16x32_bf16 layouts (HW-verified m89/m91):
//   A-frag: m = lane&15, k = quad*8 + j   (quad = lane>>4)
//   B-frag: n = lane&15, k = quad*8 + j
//   C/D:    col = lane&15, row = quad*4 + reg
__global__ __launch_bounds__(256) void mlp_kernel(const u16* __restrict__ Xb,
                                                  const u16* __restrict__ W1T,
                                                  const float* __restrict__ b1,
                                                  const u16* __restrict__ W2T,
                                                  const float* __restrict__ b2,
                                                  float* __restrict__ O,
                                                  int M) {
    __shared__ __align__(16) u16 sA[64][136];
    __shared__ __align__(16) u16 sW[128][136];
    __shared__ float sB[128];

    const int tid = threadIdx.x;
    const int m0 = blockIdx.x * 64;
    const int wave = tid >> 6, lane = tid & 63;
    const int lrow = lane & 15, quad = lane >> 4;
    const int warow = wave * 16;

    // stage W1T (32 KB, L2-hot): 2048 uint4
    for (int i = tid; i < 2048; i += 256) {
        int n = i >> 4, c8 = i & 15;
        *(uint4*)((char*)(&sW[0][0]) + n * 272 + c8 * 16) = ((const uint4*)W1T)[i];
    }
    if (tid < 128) sB[tid] = b1[tid];

    // stage X tile (bf16): 1024 uint4, zero-pad rows >= M
    for (int i = tid; i < 1024; i += 256) {
        int r = i >> 4, c8 = i & 15;
        int gr = m0 + r;
        uint4 v = make_uint4(0u, 0u, 0u, 0u);
        if (gr < M) v = *(const uint4*)(Xb + (size_t)gr * DF + c8 * 8);
        *(uint4*)((char*)(&sA[0][0]) + r * 272 + c8 * 16) = v;
    }
    __syncthreads();

    {   // phase A: H = relu(X@W1 + b1) -> back into sA (own rows only)
        f32x4 acc[8];
#pragma unroll
        for (int nt = 0; nt < 8; ++nt) acc[nt] = (f32x4){0.f, 0.f, 0.f, 0.f};
#pragma unroll
        for (int kk = 0; kk < 4; ++kk) {
            bf16x8 a = *(const bf16x8*)((const char*)(&sA[0][0]) + (warow + lrow) * 272 + kk * 64 + quad * 16);
#pragma unroll
            for (int nt = 0; nt < 8; ++nt) {
                bf16x8 b = *(const bf16x8*)((const char*)(&sW[0][0]) + (nt * 16 + lrow) * 272 + kk * 64 + quad * 16);
                acc[nt] = __builtin_amdgcn_mfma_f32_16x16x32_bf16(a, b, acc[nt], 0, 0, 0);
            }
        }
#pragma unroll
        for (int nt = 0; nt < 8; ++nt) {
            int col = nt * 16 + lrow;
            float bc = sB[col];
#pragma unroll
            for (int r = 0; r < 4; ++r)
                sA[warow + quad * 4 + r][col] = f2bf(fmaxf(acc[nt][r] + bc, 0.0f));
        }
    }
    __syncthreads();

    // stage W2T
    for (int i = tid; i < 2048; i += 256) {
        int n = i >> 4, c8 = i & 15;
        *(uint4*)((char*)(&sW[0][0]) + n * 272 + c8 * 16) = ((const uint4*)W2T)[i];
    }
    if (tid < 128) sB[tid] = b2[tid];
    __syncthreads();

    {   // phase B: O = H@W2 + b2, store f32
        f32x4 acc[8];
#pragma unroll
        for (int nt = 0; nt < 8; ++nt) acc[nt] = (f32x4){0.f, 0.f, 0.f, 0.f};
#pragma unroll
        for (int kk = 0; kk < 4; ++kk) {
            bf16x8 a = *(const bf16x8*)((const char*)(&sA[0][0]) + (warow + lrow) * 272 + kk * 64 + quad * 16);
#pragma unroll
            for (int nt = 0; nt < 8; ++nt) {
                bf16x8 b = *(const bf16x8*)((const char*)(&sW[0][0]) + (nt * 16 + lrow) * 272 + kk * 64 + quad * 16);
                acc[nt] = __builtin_amdgcn_mfma_f32_16x16x32_bf16(a, b, acc[nt], 0, 0, 0);
            }
        }
#pragma unroll
        for (int nt = 0; nt < 8; ++nt) {
            int col = nt * 16 + lrow;
            float bc = sB[col];
#pragma unroll
            for (int r = 0; r < 4; ++r) {
                int grow = m0 + warow + quad * 4 + r;
                if (grow < M) O[(size_t)grow * DF + col] = acc[nt][r] + bc;
            }
        }
    }
}

extern "C" void kernel_launch(void* const* d_in, const int* in_sizes, int n_in,
                              void* d_out, int out_size, void* d_ws, size_t ws_size,
                              hipStream_t stream) {
    // I/O contract (pinned): floats f32, indices int32 (int64 auto-detect
    // kept as insurance), output f32.
    const float* nfeats = (const float*)d_in[0];
    const void*  src    = d_in[1];
    const void*  dst    = d_in[2];
    const float* W1     = (const float*)d_in[3];
    const float* b1     = (const float*)d_in[4];
    const float* W2     = (const float*)d_in[5];
    const float* b2     = (const float*)d_in[6];
    const float* alpha  = (const float*)d_in[7];

    // Workspace (25.9 MB; 26.4 MB proven safe by prior session R2):
    //   counts   u32[50176]        @ 0
    //   edge_src int[50000*64]     @ 200704    (12.8 MB buckets)
    //   flag     u32               @ 13000704
    //   W1T bf16 u16[16384]        @ 13000720
    //   W2T bf16 u16[16384]        @ 13033488
    //   X   bf16 u16[6400000]      @ 13066256  (16-aligned)
    char* ws = (char*)d_ws;
    u32* counts   = (u32*)ws;
    int* edge_src = (int*)(ws + 200704);
    u32* flag     = (u32*)(ws + 13000704);
    u16* W1T      = (u16*)(ws + 13000720);
    u16* W2T      = (u16*)(ws + 13033488);
    u16* X        = (u16*)(ws + 13066256);

    hipMemsetAsync(counts, 0, 200704, stream);
    detect_kernel<<<1, 256, 0, stream>>>((const u32*)src, flag);
    wconv_kernel<<<128, 256, 0, stream>>>(W1, W2, W1T, W2T);
    fill_kernel<<<(NEDGES + 1023) / 1024, 256, 0, stream>>>(src, dst, flag, counts, edge_src);
    gather_kernel<<<NNODES / 4, 256, 0, stream>>>(nfeats, counts, edge_src, alpha, X);
    mlp_kernel<<<(NNODES + 63) / 64, 256, 0, stream>>>(X, W1T, b1, W2T, b2, (float*)d_out, NNODES);
}

// Round 2
// 187.574 us; speedup vs baseline: 1.4335x; 1.1506x over previous
//
#include <hip/hip_runtime.h>

typedef unsigned int u32;
typedef unsigned short u16;
typedef long long i64;

#define NNODES 50000
#define NEDGES 800000
#define DF 128
#define CAP 64     // bucket capacity: Poisson(16) tail P(c>64) ~ 1e-19/node
#define NBINS 196  // dst>>8 : 256-dst bins, 196 covers 50176
#define BINCAP 5120 // per-bin edge capacity: lambda=4096, +16 sigma
#define EPB 4096   // edges per block in bin pass

typedef __bf16 bf16x8 __attribute__((ext_vector_type(8)));
typedef float f32x4 __attribute__((ext_vector_type(4)));

__device__ __forceinline__ u16 f2bf(float f) {
    union { float f; u32 i; } v; v.f = f;
    u32 u = v.i;
    return (u16)((u + 0x7fffu + ((u >> 16) & 1u)) >> 16);  // RNE
}

// ------- 0. detect index dtype + zero bin cursors -----------------------
__global__ __launch_bounds__(256) void detect_kernel(const u32* __restrict__ src_w,
                                                     u32* __restrict__ flag,
                                                     u32* __restrict__ cursors) {
    __shared__ int any_nz;
    cursors[threadIdx.x] = 0u;           // NBINS=196 <= 256
    if (threadIdx.x == 0) any_nz = 0;
    __syncthreads();
    if (src_w[2 * threadIdx.x + 1] != 0u) atomicOr(&any_nz, 1);
    __syncthreads();
    if (threadIdx.x == 0) *flag = (any_nz == 0) ? 1u : 0u;  // 1 = int64
}

// ------- 1a. LDS-staged radix bin by dst>>8 -----------------------------
// Packs each edge to u32 (src | dst<<16; both < 65536). Per-block LDS
// histogram -> one global cursor atomic per bin per block -> coalesced
// runs (~21 edges = 84B per bin per block). Kills the cross-XCD 4B-store
// line bouncing that made the old fill write 48.7 MB for 3.2 MB payload.
__global__ __launch_bounds__(256) void bin_kernel(const void* __restrict__ src,
                                                  const void* __restrict__ dst,
                                                  const u32* __restrict__ flag,
                                                  u32* __restrict__ cursors,
                                                  u32* __restrict__ binbuf) {
    __shared__ u32 s_cnt[NBINS];
    __shared__ u32 s_base[NBINS];
    int t = threadIdx.x;
    for (int i = t; i < NBINS; i += 256) s_cnt[i] = 0u;
    __syncthreads();

    bool is64 = (*flag != 0u);
    int e0 = blockIdx.x * EPB + t;
    u32 pk[16];
#pragma unroll
    for (int i = 0; i < 16; ++i) {
        int e = e0 + i * 256;
        pk[i] = 0xFFFFFFFFu;             // sentinel: src=0xFFFF impossible (<50000)
        if (e < NEDGES) {
            int s, d;
            if (is64) { s = (int)((const i64*)src)[e]; d = (int)((const i64*)dst)[e]; }
            else      { s = ((const int*)src)[e];      d = ((const int*)dst)[e]; }
            pk[i] = (u32)s | ((u32)d << 16);
            atomicAdd(&s_cnt[(u32)d >> 8], 1u);
        }
    }
    __syncthreads();
    if (t < NBINS) {
        s_base[t] = atomicAdd(&cursors[t], s_cnt[t]);
        s_cnt[t] = 0u;                   // becomes the within-block offset
    }
    __syncthreads();
#pragma unroll
    for (int i = 0; i < 16; ++i) {
        if (pk[i] != 0xFFFFFFFFu) {
            u32 bin = pk[i] >> 24;       // == dst>>8
            u32 off = s_base[bin] + atomicAdd(&s_cnt[bin], 1u);
            if (off < BINCAP) binbuf[bin * BINCAP + off] = pk[i];
        }
    }
}

// ------- 1b. per-bin bucket build: all atomics in LDS -------------------
// One block owns one bin = 256 dsts = a private 64KB slice of edge_src.
// Every bucket line is dirtied by exactly one block -> written back once.
// Writes counts wholesale (replaces the counts memset).
__global__ __launch_bounds__(256) void build_kernel(const u32* __restrict__ cursors,
                                                    const u32* __restrict__ binbuf,
                                                    u32* __restrict__ counts,
                                                    int* __restrict__ edge_src) {
    __shared__ u32 cnt[256];
    int t = threadIdx.x;
    cnt[t] = 0u;
    __syncthreads();
    int b = blockIdx.x;
    int n = (int)cursors[b]; if (n > BINCAP) n = BINCAP;
    for (int i = t; i < n; i += 256) {
        u32 pk = binbuf[b * BINCAP + i];
        int srcv = (int)(pk & 0xFFFFu);
        int dl = (int)((pk >> 16) & 0xFFu);
        u32 pos = atomicAdd(&cnt[dl], 1u);
        if (pos < CAP) edge_src[(((b << 8) + dl) << 6) + (int)pos] = srcv;
    }
    __syncthreads();
    counts[(b << 8) + t] = cnt[t];       // up to 50175 < 50176
}

// ------- 2. gather: dedup + sum + combine -> X (bf16, in ws) ------------
// One wave per dst node, entirely wave-private (no block barriers).
__global__ __launch_bounds__(256) void gather_kernel(const float* __restrict__ nf,
                                                     const u32* __restrict__ counts,
                                                     const int* __restrict__ edge_src,
                                                     const float* __restrict__ alpha,
                                                     u16* __restrict__ X) {
    __shared__ __align__(16) int s_kept[4][CAP];
    int w = threadIdx.x >> 6, lane = threadIdx.x & 63;
    int d = blockIdx.x * 4 + w;          // grid = NNODES/4 exactly
    int c = (int)counts[d];
    int cc = c < CAP ? c : CAP;

    // issue the dst row + alpha loads early; they overlap the dedup phase
    float al = 1.0f + alpha[0];
    float2 dv = *(const float2*)(nf + (size_t)d * DF + 2 * lane);

    int si = 0;
    bool k = false;
    if (lane < cc) { si = edge_src[(d << 6) + lane]; k = true; }
    for (int j = 0; j < cc - 1; ++j) {
        int v = __shfl(si, j, 64);
        if (j < lane && v == si) k = false;
    }
    unsigned long long m = __ballot(k);
    if (k) s_kept[w][__popcll(m & ((1ull << lane) - 1ull))] = si;
    int nk = __popcll(m);
    __builtin_amdgcn_wave_barrier();     // wave-private LDS: no __syncthreads

    float a0 = 0.f, a1 = 0.f;
    int i = 0;
    for (; i + 8 <= nk; i += 8) {        // 8 independent 512B row loads in flight
        int4 q0 = *(const int4*)&s_kept[w][i];
        int4 q1 = *(const int4*)&s_kept[w][i + 4];
        float2 v0 = *(const float2*)(nf + (size_t)q0.x * DF + 2 * lane);
        float2 v1 = *(const float2*)(nf + (size_t)q0.y * DF + 2 * lane);
        float2 v2 = *(const float2*)(nf + (size_t)q0.z * DF + 2 * lane);
        float2 v3 = *(const float2*)(nf + (size_t)q0.w * DF + 2 * lane);
        float2 v4 = *(const float2*)(nf + (size_t)q1.x * DF + 2 * lane);
        float2 v5 = *(const float2*)(nf + (size_t)q1.y * DF + 2 * lane);
        float2 v6 = *(const float2*)(nf + (size_t)q1.z * DF + 2 * lane);
        float2 v7 = *(const float2*)(nf + (size_t)q1.w * DF + 2 * lane);
        a0 += ((v0.x + v1.x) + (v2.x + v3.x)) + ((v4.x + v5.x) + (v6.x + v7.x));
        a1 += ((v0.y + v1.y) + (v2.y + v3.y)) + ((v4.y + v5.y) + (v6.y + v7.y));
    }
    for (; i + 4 <= nk; i += 4) {
        int4 q = *(const int4*)&s_kept[w][i];
        float2 v0 = *(const float2*)(nf + (size_t)q.x * DF + 2 * lane);
        float2 v1 = *(const float2*)(nf + (size_t)q.y * DF + 2 * lane);
        float2 v2 = *(const float2*)(nf + (size_t)q.z * DF + 2 * lane);
        float2 v3 = *(const float2*)(nf + (size_t)q.w * DF + 2 * lane);
        a0 += (v0.x + v1.x) + (v2.x + v3.x);
        a1 += (v0.y + v1.y) + (v2.y + v3.y);
    }
    for (; i < nk; ++i) {
        int s = s_kept[w][i];
        float2 v = *(const float2*)(nf + (size_t)s * DF + 2 * lane);
        a0 += v.x; a1 += v.y;
    }

    u32 pk = (u32)f2bf(fmaf(al, dv.x, a0)) | ((u32)f2bf(fmaf(al, dv.y, a1)) << 16);
    *(u32*)(X + (size_t)d * DF + 2 * lane) = pk;
}

// ------- 3. W pre-convert: W[k][n] f32 -> WT[n][k] bf16 -----------------
__global__ __launch_bounds__(256) void wconv_kernel(const float* __restrict__ W1,
                                                    const float* __restrict__ W2,
                                                    u16* __restrict__ W1T,
                                                    u16* __restrict__ W2T) {
    int i = blockIdx.x * 256 + threadIdx.x;   // 32768 threads
    const float* W = (i < 16384) ? W1 : W2;
    u16* T = (i < 16384) ? W1T : W2T;
    int j = i & 16383;
    int n = j >> 7, k = j & 127;
    T[j] = f2bf(W[k * 128 + n]);
}

// ------- 4. fused MFMA MLP: O = relu(X@W1+b1)@W2 + b2  (bf16 in, f32 out)
__global__ __launch_bounds__(256) void mlp_kernel(const u16* __restrict__ Xb,
                                                  const u16* __restrict__ W1T,
                                                  const float* __restrict__ b1,
                                                  const u16* __restrict__ W2T,
                                                  const float* __restrict__ b2,
                                                  float* __restrict__ O,
                                                  int M) {
    __shared__ __align__(16) u16 sA[64][136];
    __shared__ __align__(16) u16 sW[128][136];
    __shared__ float sB[128];

    const int tid = threadIdx.x;
    const int m0 = blockIdx.x * 64;
    const int wave = tid >> 6, lane = tid & 63;
    const int lrow = lane & 15, quad = lane >> 4;
    const int warow = wave * 16;

    // stage W1T (32 KB, L2-hot): 2048 uint4
    for (int i = tid; i < 2048; i += 256) {
        int n = i >> 4, c8 = i & 15;
        *(uint4*)((char*)(&sW[0][0]) + n * 272 + c8 * 16) = ((const uint4*)W1T)[i];
    }
    if (tid < 128) sB[tid] = b1[tid];

    // stage X tile (bf16): 1024 uint4, zero-pad rows >= M
    for (int i = tid; i < 1024; i += 256) {
        int r = i >> 4, c8 = i & 15;
        int gr = m0 + r;
        uint4 v = make_uint4(0u, 0u, 0u, 0u);
        if (gr < M) v = *(const uint4*)(Xb + (size_t)gr * DF + c8 * 8);
        *(uint4*)((char*)(&sA[0][0]) + r * 272 + c8 * 16) = v;
    }
    __syncthreads();

    {   // phase A: H = relu(X@W1 + b1) -> back into sA (own rows only)
        f32x4 acc[8];
#pragma unroll
        for (int nt = 0; nt < 8; ++nt) acc[nt] = (f32x4){0.f, 0.f, 0.f, 0.f};
#pragma unroll
        for (int kk = 0; kk < 4; ++kk) {
            bf16x8 a = *(const bf16x8*)((const char*)(&sA[0][0]) + (warow + lrow) * 272 + kk * 64 + quad * 16);
#pragma unroll
            for (int nt = 0; nt < 8; ++nt) {
                bf16x8 b = *(const bf16x8*)((const char*)(&sW[0][0]) + (nt * 16 + lrow) * 272 + kk * 64 + quad * 16);
                acc[nt] = __builtin_amdgcn_mfma_f32_16x16x32_bf16(a, b, acc[nt], 0, 0, 0);
            }
        }
#pragma unroll
        for (int nt = 0; nt < 8; ++nt) {
            int col = nt * 16 + lrow;
            float bc = sB[col];
#pragma unroll
            for (int r = 0; r < 4; ++r)
                sA[warow + quad * 4 + r][col] = f2bf(fmaxf(acc[nt][r] + bc, 0.0f));
        }
    }
    __syncthreads();

    // stage W2T
    for (int i = tid; i < 2048; i += 256) {
        int n = i >> 4, c8 = i & 15;
        *(uint4*)((char*)(&sW[0][0]) + n * 272 + c8 * 16) = ((const uint4*)W2T)[i];
    }
    if (tid < 128) sB[tid] = b2[tid];
    __syncthreads();

    {   // phase B: O = H@W2 + b2, store f32
        f32x4 acc[8];
#pragma unroll
        for (int nt = 0; nt < 8; ++nt) acc[nt] = (f32x4){0.f, 0.f, 0.f, 0.f};
#pragma unroll
        for (int kk = 0; kk < 4; ++kk) {
            bf16x8 a = *(const bf16x8*)((const char*)(&sA[0][0]) + (warow + lrow) * 272 + kk * 64 + quad * 16);
#pragma unroll
            for (int nt = 0; nt < 8; ++nt) {
                bf16x8 b = *(const bf16x8*)((const char*)(&sW[0][0]) + (nt * 16 + lrow) * 272 + kk * 64 + quad * 16);
                acc[nt] = __builtin_amdgcn_mfma_f32_16x16x32_bf16(a, b, acc[nt], 0, 0, 0);
            }
        }
#pragma unroll
        for (int nt = 0; nt < 8; ++nt) {
            int col = nt * 16 + lrow;
            float bc = sB[col];
#pragma unroll
            for (int r = 0; r < 4; ++r) {
                int grow = m0 + warow + quad * 4 + r;
                if (grow < M) O[(size_t)grow * DF + col] = acc[nt][r] + bc;
            }
        }
    }
}

extern "C" void kernel_launch(void* const* d_in, const int* in_sizes, int n_in,
                              void* d_out, int out_size, void* d_ws, size_t ws_size,
                              hipStream_t stream) {
    const float* nfeats = (const float*)d_in[0];
    const void*  src    = d_in[1];
    const void*  dst    = d_in[2];
    const float* W1     = (const float*)d_in[3];
    const float* b1     = (const float*)d_in[4];
    const float* W2     = (const float*)d_in[5];
    const float* b2     = (const float*)d_in[6];
    const float* alpha  = (const float*)d_in[7];

    // Workspace (25.9 MB; 26.4 MB proven safe):
    //   counts   u32[50176]        @ 0          (written wholesale by build)
    //   edge_src int[50000*64]     @ 200704     (12.8 MB buckets)
    //   flag     u32               @ 13000704
    //   W1T bf16 u16[16384]        @ 13000720
    //   W2T bf16 u16[16384]        @ 13033488
    //   X   bf16 u16[6400000]      @ 13066256   (12.8 MB)
    //   binbuf u32[196*5120]       @ 13066256   (4.0 MB, ALIASES X: binbuf
    //                                            dies in build, X born in gather)
    //   cursors u32[256]           @ 25866256
    char* ws = (char*)d_ws;
    u32* counts   = (u32*)ws;
    int* edge_src = (int*)(ws + 200704);
    u32* flag     = (u32*)(ws + 13000704);
    u16* W1T      = (u16*)(ws + 13000720);
    u16* W2T      = (u16*)(ws + 13033488);
    u16* X        = (u16*)(ws + 13066256);
    u32* binbuf   = (u32*)(ws + 13066256);
    u32* cursors  = (u32*)(ws + 25866256);

    detect_kernel<<<1, 256, 0, stream>>>((const u32*)src, flag, cursors);
    wconv_kernel<<<128, 256, 0, stream>>>(W1, W2, W1T, W2T);
    bin_kernel<<<(NEDGES + EPB - 1) / EPB, 256, 0, stream>>>(src, dst, flag, cursors, binbuf);
    build_kernel<<<NBINS, 256, 0, stream>>>(cursors, binbuf, counts, edge_src);
    gather_kernel<<<NNODES / 4, 256, 0, stream>>>(nfeats, counts, edge_src, alpha, X);
    mlp_kernel<<<(NNODES + 63) / 64, 256, 0, stream>>>(X, W1T, b1, W2T, b2, (float*)d_out, NNODES);
}